// Round 5
// baseline (470.702 us; speedup 1.0000x reference)
//
#include <hip/hip_runtime.h>
#include <math.h>

// Problem constants
#define T_DIM 1024
#define N_DIM 8192
#define M_TOT (T_DIM * N_DIM)      // 8,388,608
#define NVEC  (M_TOT / 4)          // 2,097,152 vec4 elements
#define NV4   (N_DIM / 4)          // 2048 vec4 per row
#define L_CHUNK 8
#define C_CHUNKS 128               // T_DIM / L_CHUNK

#define kGAMMA 0.99f
#define kGLAM  (0.99f * 0.95f)

// ws layout (24 MB + 256 B; <= 32.25 MB proven in R1):
//   [0, 64)        acc doubles: 0=sum g, 1=sum g^2, 2=action sum, 3=value sum,
//                  4=entropy sum, 5=mu, 6=inv(std+1e-5)
//   +256           b16 [T][N] ushort (16 MB) -- k_gae overwrites with gae16
//   +256+16MB      A [C][N] float (4 MB)     -- k_ginc overwrites with g_in
//   +256+20MB      B [C][N] float (4 MB)

typedef float  vf4 __attribute__((ext_vector_type(4)));
typedef unsigned short vu4 __attribute__((ext_vector_type(4)));

__device__ __forceinline__ float4 nt4(const float4* p) {
    vf4 v = __builtin_nontemporal_load((const vf4*)p);
    return make_float4(v.x, v.y, v.z, v.w);
}
__device__ __forceinline__ ushort4 ntu4(const ushort4* p) {
    vu4 v = __builtin_nontemporal_load((const vu4*)p);
    ushort4 o; o.x = v.x; o.y = v.y; o.z = v.z; o.w = v.w; return o;
}

__device__ __forceinline__ unsigned short f2bf(float f) {
    unsigned int u = __float_as_uint(f);
    u += 0x7fffu + ((u >> 16) & 1u);        // round-to-nearest-even
    return (unsigned short)(u >> 16);
}
__device__ __forceinline__ float bf2f(unsigned short h) {
    return __uint_as_float(((unsigned int)h) << 16);
}

// ---------------------------------------------------------------------------
// P1: fused prep+chunk. Thread (c, j): row-serial descending-t loop with
// vnext carry; computes b_t (stored bf16, a-bit in LSB) AND composes the
// chunk affine map (A,B). Block 0 zeros the accumulators.
__global__ __launch_bounds__(256) void k_pc(
    const float4* __restrict__ r4,
    const float4* __restrict__ m4,     // (T+1) rows
    const float4* __restrict__ bm4,    // (T+1) rows
    const float4* __restrict__ vp4,    // (T+1) rows
    const float4* __restrict__ lv4,    // (N,)
    ushort4* __restrict__ b16,
    float4* __restrict__ A_out,
    float4* __restrict__ B_out,
    double* __restrict__ acc)
{
    if (blockIdx.x == 0 && threadIdx.x < 8) acc[threadIdx.x] = 0.0;

    const int g  = blockIdx.x * 256 + threadIdx.x;   // 0 .. C*NV4-1
    const int j  = g & (NV4 - 1);
    const int c  = g >> 11;
    const int t0 = c * L_CHUNK;

    float4 vnext = (c == C_CHUNKS - 1) ? lv4[j] : vp4[(t0 + L_CHUNK) * NV4 + j];
    float4 Aa = make_float4(1.f, 1.f, 1.f, 1.f);
    float4 Bb = make_float4(0.f, 0.f, 0.f, 0.f);

    #pragma unroll
    for (int i = L_CHUNK - 1; i >= 0; --i) {
        const int idx = (t0 + i) * NV4 + j;
        const float4 r  = nt4(r4 + idx);
        const float4 v  = vp4[idx];                  // vp reused by k_gae: cache
        const float4 m  = nt4(m4 + idx + NV4);       // row t+1
        const float4 bb = nt4(bm4 + idx + NV4);      // row t+1

        ushort4 o;
        {
            const float b = (fmaf(kGAMMA * m.x, vnext.x, r.x) - v.x) * bb.x;
            const float a = kGLAM * m.x * bb.x;
            Aa.x = a * Aa.x; Bb.x = fmaf(a, Bb.x, b);
            o.x = (unsigned short)((f2bf(b) & 0xFFFEu) | ((m.x * bb.x > 0.5f) ? 1u : 0u));
        }
        {
            const float b = (fmaf(kGAMMA * m.y, vnext.y, r.y) - v.y) * bb.y;
            const float a = kGLAM * m.y * bb.y;
            Aa.y = a * Aa.y; Bb.y = fmaf(a, Bb.y, b);
            o.y = (unsigned short)((f2bf(b) & 0xFFFEu) | ((m.y * bb.y > 0.5f) ? 1u : 0u));
        }
        {
            const float b = (fmaf(kGAMMA * m.z, vnext.z, r.z) - v.z) * bb.z;
            const float a = kGLAM * m.z * bb.z;
            Aa.z = a * Aa.z; Bb.z = fmaf(a, Bb.z, b);
            o.z = (unsigned short)((f2bf(b) & 0xFFFEu) | ((m.z * bb.z > 0.5f) ? 1u : 0u));
        }
        {
            const float b = (fmaf(kGAMMA * m.w, vnext.w, r.w) - v.w) * bb.w;
            const float a = kGLAM * m.w * bb.w;
            Aa.w = a * Aa.w; Bb.w = fmaf(a, Bb.w, b);
            o.w = (unsigned short)((f2bf(b) & 0xFFFEu) | ((m.w * bb.w > 0.5f) ? 1u : 0u));
        }
        b16[idx] = o;
        vnext = v;
    }
    A_out[c * NV4 + j] = Aa;
    B_out[c * NV4 + j] = Bb;
}

// ---------------------------------------------------------------------------
// P2: per-env serial scan over the 128 chunk maps; writes each chunk's
// incoming gae. g_in ALIASES A (load batch, then store over it).
__global__ __launch_bounds__(256) void k_ginc(
    const float* __restrict__ A_in,
    const float* __restrict__ B_in,
    float* __restrict__ g_in)          // aliases A_in
{
    const int n = blockIdx.x * 256 + threadIdx.x;   // 0..N-1
    float g = 0.0f;
    constexpr int PB = 16;
    for (int cb = C_CHUNKS - PB; cb >= 0; cb -= PB) {
        float Ar[PB], Br[PB];
        #pragma unroll
        for (int i = 0; i < PB; ++i) {
            Ar[i] = A_in[(cb + i) * N_DIM + n];
            Br[i] = B_in[(cb + i) * N_DIM + n];
        }
        #pragma unroll
        for (int i = PB - 1; i >= 0; --i) {
            g_in[(cb + i) * N_DIM + n] = g;
            g = fmaf(Ar[i], g, Br[i]);
        }
    }
}

// ---------------------------------------------------------------------------
// P3: recompute gae per element from b16 + g_in (row-serial), write gae16 in
// place, fuse value loss (vp cached, nv nontemporal) and sum/sum2 of gae.
__device__ __forceinline__ void gae_comp(float& gae, unsigned short h,
                                         float v, float nvv,
                                         float& sg, float& sg2, float& v_s) {
    const float bf = bf2f(h);
    const float a  = (h & 1u) ? kGLAM : 0.0f;
    gae = fmaf(a, gae, bf);
    sg += gae;
    sg2 = fmaf(gae, gae, sg2);
    const float q  = nvv - v;
    const float e1 = q - gae;
    const float e2 = fminf(fmaxf(q, -0.2f), 0.2f) - gae;
    v_s += fmaxf(e1 * e1, e2 * e2);
}

__global__ __launch_bounds__(256) void k_gae(
    ushort4* __restrict__ bg16,        // in: b16, out: gae16
    const float4* __restrict__ g_in4,
    const float4* __restrict__ vp4,
    const float4* __restrict__ nv4,
    double* __restrict__ acc)
{
    const int g  = blockIdx.x * 256 + threadIdx.x;   // 0 .. C*NV4-1
    const int j  = g & (NV4 - 1);
    const int c  = g >> 11;
    const int t0 = c * L_CHUNK;

    float4 gae = g_in4[c * NV4 + j];
    float sg = 0.f, sg2 = 0.f, v_s = 0.f;

    #pragma unroll
    for (int i = L_CHUNK - 1; i >= 0; --i) {
        const int idx = (t0 + i) * NV4 + j;
        const ushort4 h = bg16[idx];
        const float4  v = vp4[idx];
        const float4  q = nt4(nv4 + idx);
        gae_comp(gae.x, h.x, v.x, q.x, sg, sg2, v_s);
        gae_comp(gae.y, h.y, v.y, q.y, sg, sg2, v_s);
        gae_comp(gae.z, h.z, v.z, q.z, sg, sg2, v_s);
        gae_comp(gae.w, h.w, v.w, q.w, sg, sg2, v_s);
        ushort4 o;
        o.x = f2bf(gae.x); o.y = f2bf(gae.y); o.z = f2bf(gae.z); o.w = f2bf(gae.w);
        bg16[idx] = o;
    }

    double d0 = (double)sg, d1 = (double)sg2, d2 = (double)v_s;
    #pragma unroll
    for (int off = 32; off > 0; off >>= 1) {
        d0 += __shfl_down(d0, off, 64);
        d1 += __shfl_down(d1, off, 64);
        d2 += __shfl_down(d2, off, 64);
    }
    __shared__ double sh[3][4];
    const int wid = threadIdx.x >> 6, lane = threadIdx.x & 63;
    if (lane == 0) { sh[0][wid] = d0; sh[1][wid] = d1; sh[2][wid] = d2; }
    __syncthreads();
    if (threadIdx.x == 0) {
        double t0s = 0, t1s = 0, t2s = 0;
        #pragma unroll
        for (int w = 0; w < 4; ++w) { t0s += sh[0][w]; t1s += sh[1][w]; t2s += sh[2][w]; }
        atomicAdd(&acc[0], t0s);
        atomicAdd(&acc[1], t1s);
        atomicAdd(&acc[3], t2s);
    }
}

// ---------------------------------------------------------------------------
__global__ void k_stats(double* __restrict__ acc) {
    const double M = (double)M_TOT;
    const double sum = acc[0], sum2 = acc[1];
    const double mu = sum / M;
    double var = (sum2 - sum * sum / M) / (M - 1.0);
    if (var < 0.0) var = 0.0;
    acc[5] = mu;
    acc[6] = 1.0 / (sqrt(var) + 1e-5);
}

// ---------------------------------------------------------------------------
// P5: action loss + entropy. LOOP-FREE: 8192 blocks, one vec4 per thread per
// stream; nontemporal on the three read-once fp32 streams.
__global__ __launch_bounds__(256) void k_loss(
    const ushort4* __restrict__ gae16,
    const float4* __restrict__ lp4,
    const float4* __restrict__ plp4,
    const float4* __restrict__ ent4,
    double* __restrict__ acc)
{
    const int i = blockIdx.x * 256 + threadIdx.x;    // 0 .. NVEC-1

    const ushort4 G = gae16[i];
    const float4  L = nt4(lp4 + i);
    const float4  P = nt4(plp4 + i);
    const float4  E = nt4(ent4 + i);

    const float mu   = (float)acc[5];
    const float invs = (float)acc[6];

    const float gs[4] = {bf2f(G.x), bf2f(G.y), bf2f(G.z), bf2f(G.w)};
    const float ls[4] = {L.x, L.y, L.z, L.w};
    const float ps[4] = {P.x, P.y, P.z, P.w};
    float a_s = 0.f;
    #pragma unroll
    for (int c = 0; c < 4; ++c) {
        const float x  = (gs[c] - mu) * invs;
        const float r  = __expf(ls[c] - ps[c]);
        const float rc = fminf(fmaxf(r, 0.8f), 1.2f);
        a_s += fminf(r * x, rc * x);
    }
    float e_s = E.x + E.y + E.z + E.w;

    double d0 = (double)a_s, d1 = (double)e_s;
    #pragma unroll
    for (int off = 32; off > 0; off >>= 1) {
        d0 += __shfl_down(d0, off, 64);
        d1 += __shfl_down(d1, off, 64);
    }
    __shared__ double sh[2][4];
    const int wid = threadIdx.x >> 6, lane = threadIdx.x & 63;
    if (lane == 0) { sh[0][wid] = d0; sh[1][wid] = d1; }
    __syncthreads();
    if (threadIdx.x == 0) {
        double t0s = 0, t1s = 0;
        #pragma unroll
        for (int w = 0; w < 4; ++w) { t0s += sh[0][w]; t1s += sh[1][w]; }
        atomicAdd(&acc[2], t0s);
        atomicAdd(&acc[4], t1s);
    }
}

// ---------------------------------------------------------------------------
__global__ void k_final(const double* __restrict__ acc, float* __restrict__ out) {
    const double M = (double)M_TOT;
    const double loss = 0.25 * acc[3] / M - acc[2] / M - 0.01 * acc[4] / M;
    out[0] = (float)loss;
}

// ---------------------------------------------------------------------------
extern "C" void kernel_launch(void* const* d_in, const int* in_sizes, int n_in,
                              void* d_out, int out_size, void* d_ws, size_t ws_size,
                              hipStream_t stream) {
    const float* rewards     = (const float*)d_in[0];   // (T, N)
    const float* masks       = (const float*)d_in[1];   // (T+1, N)
    const float* bad_masks   = (const float*)d_in[2];   // (T+1, N)
    const float* value_preds = (const float*)d_in[3];   // (T+1, N)
    const float* last_value  = (const float*)d_in[4];   // (N,)
    const float* log_prob    = (const float*)d_in[5];   // (T, N)
    const float* prev_lp     = (const float*)d_in[6];   // (T, N)
    const float* new_value   = (const float*)d_in[7];   // (T, N)
    const float* dist_ent    = (const float*)d_in[8];   // (T, N)

    char* ws = (char*)d_ws;
    double* acc = (double*)ws;
    unsigned short* b16 = (unsigned short*)(ws + 256);
    float* A = (float*)(ws + 256 + (size_t)M_TOT * 2);
    float* B = (float*)(ws + 256 + (size_t)M_TOT * 2 + (size_t)C_CHUNKS * N_DIM * 4);

    const int cn_blocks = (C_CHUNKS * NV4) / 256;   // 1024

    k_pc<<<cn_blocks, 256, 0, stream>>>((const float4*)rewards,
                                        (const float4*)masks,
                                        (const float4*)bad_masks,
                                        (const float4*)value_preds,
                                        (const float4*)last_value,
                                        (ushort4*)b16, (float4*)A, (float4*)B, acc);
    k_ginc<<<N_DIM / 256, 256, 0, stream>>>(A, B, A /* g_in aliases A */);
    k_gae<<<cn_blocks, 256, 0, stream>>>((ushort4*)b16,
                                         (const float4*)A /* g_in */,
                                         (const float4*)value_preds,
                                         (const float4*)new_value, acc);
    k_stats<<<1, 1, 0, stream>>>(acc);
    k_loss<<<NVEC / 256, 256, 0, stream>>>((const ushort4*)b16 /* gae16 */,
                                           (const float4*)log_prob,
                                           (const float4*)prev_lp,
                                           (const float4*)dist_ent, acc);
    k_final<<<1, 1, 0, stream>>>(acc, (float*)d_out);
}

// Round 6
// 274.124 us; speedup vs baseline: 1.7171x; 1.7171x over previous
//
#include <hip/hip_runtime.h>
#include <math.h>

// Problem constants
#define T_DIM 1024
#define N_DIM 8192
#define M_TOT (T_DIM * N_DIM)      // 8,388,608
#define NVEC  (M_TOT / 4)          // 2,097,152 vec4 elements
#define NV4   (N_DIM / 4)          // 2048 vec4 per row
#define L_CHUNK 8
#define C_CHUNKS 128               // T_DIM / L_CHUNK

#define PC_BLOCKS   ((C_CHUNKS * NV4) / 256)   // 1024
#define LOSS_BLOCKS 2048
#define LOSS_STRIDE (LOSS_BLOCKS * 256)        // 524,288; NVEC = 4 * LOSS_STRIDE

#define kGAMMA 0.99f
#define kGLAM  (0.99f * 0.95f)

// ws layout (~24.06 MB):
//   [0, 64)         acc doubles: 3=value sum, 5=mu, 6=inv(std+1e-5)
//   +256            pg  [1024][3] doubles (24 KB)  -- k_gae block partials
//   +32768          pl  [2048][2] doubles (32 KB)  -- k_loss block partials
//   +65536          b16 [T][N] ushort (16 MB)      -- k_gae overwrites w/ gae16
//   +65536+16MB     A   [C][N] float (4 MB)        -- k_ginc overwrites w/ g_in
//   +65536+20MB     B   [C][N] float (4 MB)

__device__ __forceinline__ unsigned short f2bf(float f) {
    unsigned int u = __float_as_uint(f);
    u += 0x7fffu + ((u >> 16) & 1u);        // round-to-nearest-even
    return (unsigned short)(u >> 16);
}
__device__ __forceinline__ float bf2f(unsigned short h) {
    return __uint_as_float(((unsigned int)h) << 16);
}

// ---------------------------------------------------------------------------
// P1: fused prep+chunk. Thread (c, j): row-serial descending-t loop with
// vnext carry; computes b_t (bf16, a-bit in LSB) AND the chunk map (A,B).
__global__ __launch_bounds__(256) void k_pc(
    const float4* __restrict__ r4,
    const float4* __restrict__ m4,     // (T+1) rows
    const float4* __restrict__ bm4,    // (T+1) rows
    const float4* __restrict__ vp4,    // (T+1) rows
    const float4* __restrict__ lv4,    // (N,)
    ushort4* __restrict__ b16,
    float4* __restrict__ A_out,
    float4* __restrict__ B_out)
{
    const int g  = blockIdx.x * 256 + threadIdx.x;   // 0 .. C*NV4-1
    const int j  = g & (NV4 - 1);
    const int c  = g >> 11;
    const int t0 = c * L_CHUNK;

    float4 vnext = (c == C_CHUNKS - 1) ? lv4[j] : vp4[(t0 + L_CHUNK) * NV4 + j];
    float4 Aa = make_float4(1.f, 1.f, 1.f, 1.f);
    float4 Bb = make_float4(0.f, 0.f, 0.f, 0.f);

    #pragma unroll
    for (int i = L_CHUNK - 1; i >= 0; --i) {
        const int idx = (t0 + i) * NV4 + j;
        const float4 r  = r4[idx];
        const float4 v  = vp4[idx];
        const float4 m  = m4[idx + NV4];             // row t+1
        const float4 bb = bm4[idx + NV4];            // row t+1

        ushort4 o;
        {
            const float b = (fmaf(kGAMMA * m.x, vnext.x, r.x) - v.x) * bb.x;
            const float a = kGLAM * m.x * bb.x;
            Aa.x = a * Aa.x; Bb.x = fmaf(a, Bb.x, b);
            o.x = (unsigned short)((f2bf(b) & 0xFFFEu) | ((m.x * bb.x > 0.5f) ? 1u : 0u));
        }
        {
            const float b = (fmaf(kGAMMA * m.y, vnext.y, r.y) - v.y) * bb.y;
            const float a = kGLAM * m.y * bb.y;
            Aa.y = a * Aa.y; Bb.y = fmaf(a, Bb.y, b);
            o.y = (unsigned short)((f2bf(b) & 0xFFFEu) | ((m.y * bb.y > 0.5f) ? 1u : 0u));
        }
        {
            const float b = (fmaf(kGAMMA * m.z, vnext.z, r.z) - v.z) * bb.z;
            const float a = kGLAM * m.z * bb.z;
            Aa.z = a * Aa.z; Bb.z = fmaf(a, Bb.z, b);
            o.z = (unsigned short)((f2bf(b) & 0xFFFEu) | ((m.z * bb.z > 0.5f) ? 1u : 0u));
        }
        {
            const float b = (fmaf(kGAMMA * m.w, vnext.w, r.w) - v.w) * bb.w;
            const float a = kGLAM * m.w * bb.w;
            Aa.w = a * Aa.w; Bb.w = fmaf(a, Bb.w, b);
            o.w = (unsigned short)((f2bf(b) & 0xFFFEu) | ((m.w * bb.w > 0.5f) ? 1u : 0u));
        }
        b16[idx] = o;
        vnext = v;
    }
    A_out[c * NV4 + j] = Aa;
    B_out[c * NV4 + j] = Bb;
}

// ---------------------------------------------------------------------------
// P2: per-env serial scan over the 128 chunk maps; writes each chunk's
// incoming gae. g_in ALIASES A (load batch, then store over it).
__global__ __launch_bounds__(256) void k_ginc(
    const float* __restrict__ A_in,
    const float* __restrict__ B_in,
    float* __restrict__ g_in)          // aliases A_in
{
    const int n = blockIdx.x * 256 + threadIdx.x;   // 0..N-1
    float g = 0.0f;
    constexpr int PB = 16;
    for (int cb = C_CHUNKS - PB; cb >= 0; cb -= PB) {
        float Ar[PB], Br[PB];
        #pragma unroll
        for (int i = 0; i < PB; ++i) {
            Ar[i] = A_in[(cb + i) * N_DIM + n];
            Br[i] = B_in[(cb + i) * N_DIM + n];
        }
        #pragma unroll
        for (int i = PB - 1; i >= 0; --i) {
            g_in[(cb + i) * N_DIM + n] = g;
            g = fmaf(Ar[i], g, Br[i]);
        }
    }
}

// ---------------------------------------------------------------------------
// P3: recompute gae per element from b16 + g_in (row-serial), write gae16 in
// place, fuse value loss and sum/sum2 of gae. Block partials -> pg (STORES).
__device__ __forceinline__ void gae_comp(float& gae, unsigned short h,
                                         float v, float nvv,
                                         float& sg, float& sg2, float& v_s) {
    const float bf = bf2f(h);
    const float a  = (h & 1u) ? kGLAM : 0.0f;
    gae = fmaf(a, gae, bf);
    sg += gae;
    sg2 = fmaf(gae, gae, sg2);
    const float q  = nvv - v;
    const float e1 = q - gae;
    const float e2 = fminf(fmaxf(q, -0.2f), 0.2f) - gae;
    v_s += fmaxf(e1 * e1, e2 * e2);
}

__global__ __launch_bounds__(256) void k_gae(
    ushort4* __restrict__ bg16,        // in: b16, out: gae16
    const float4* __restrict__ g_in4,
    const float4* __restrict__ vp4,
    const float4* __restrict__ nv4,
    double* __restrict__ pg)           // [PC_BLOCKS][3]
{
    const int g  = blockIdx.x * 256 + threadIdx.x;   // 0 .. C*NV4-1
    const int j  = g & (NV4 - 1);
    const int c  = g >> 11;
    const int t0 = c * L_CHUNK;

    float4 gae = g_in4[c * NV4 + j];
    float sg = 0.f, sg2 = 0.f, v_s = 0.f;

    #pragma unroll
    for (int i = L_CHUNK - 1; i >= 0; --i) {
        const int idx = (t0 + i) * NV4 + j;
        const ushort4 h = bg16[idx];
        const float4  v = vp4[idx];
        const float4  q = nv4[idx];
        gae_comp(gae.x, h.x, v.x, q.x, sg, sg2, v_s);
        gae_comp(gae.y, h.y, v.y, q.y, sg, sg2, v_s);
        gae_comp(gae.z, h.z, v.z, q.z, sg, sg2, v_s);
        gae_comp(gae.w, h.w, v.w, q.w, sg, sg2, v_s);
        ushort4 o;
        o.x = f2bf(gae.x); o.y = f2bf(gae.y); o.z = f2bf(gae.z); o.w = f2bf(gae.w);
        bg16[idx] = o;
    }

    double d0 = (double)sg, d1 = (double)sg2, d2 = (double)v_s;
    #pragma unroll
    for (int off = 32; off > 0; off >>= 1) {
        d0 += __shfl_down(d0, off, 64);
        d1 += __shfl_down(d1, off, 64);
        d2 += __shfl_down(d2, off, 64);
    }
    __shared__ double sh[3][4];
    const int wid = threadIdx.x >> 6, lane = threadIdx.x & 63;
    if (lane == 0) { sh[0][wid] = d0; sh[1][wid] = d1; sh[2][wid] = d2; }
    __syncthreads();
    if (threadIdx.x == 0) {
        double t0s = 0, t1s = 0, t2s = 0;
        #pragma unroll
        for (int w = 0; w < 4; ++w) { t0s += sh[0][w]; t1s += sh[1][w]; t2s += sh[2][w]; }
        pg[blockIdx.x * 3 + 0] = t0s;      // plain stores, zero contention
        pg[blockIdx.x * 3 + 1] = t1s;
        pg[blockIdx.x * 3 + 2] = t2s;
    }
}

// ---------------------------------------------------------------------------
// P4: reduce k_gae partials -> mu, inv(std+eps), value_sum. One block.
__global__ __launch_bounds__(256) void k_stats(
    const double* __restrict__ pg, double* __restrict__ acc)
{
    double s0 = 0.0, s1 = 0.0, s2 = 0.0;
    for (int i = threadIdx.x; i < PC_BLOCKS; i += 256) {
        s0 += pg[i * 3 + 0];
        s1 += pg[i * 3 + 1];
        s2 += pg[i * 3 + 2];
    }
    #pragma unroll
    for (int off = 32; off > 0; off >>= 1) {
        s0 += __shfl_down(s0, off, 64);
        s1 += __shfl_down(s1, off, 64);
        s2 += __shfl_down(s2, off, 64);
    }
    __shared__ double sh[3][4];
    const int wid = threadIdx.x >> 6, lane = threadIdx.x & 63;
    if (lane == 0) { sh[0][wid] = s0; sh[1][wid] = s1; sh[2][wid] = s2; }
    __syncthreads();
    if (threadIdx.x == 0) {
        double sum = 0, sum2 = 0, vsum = 0;
        #pragma unroll
        for (int w = 0; w < 4; ++w) { sum += sh[0][w]; sum2 += sh[1][w]; vsum += sh[2][w]; }
        const double M = (double)M_TOT;
        const double mu = sum / M;
        double var = (sum2 - sum * sum / M) / (M - 1.0);
        if (var < 0.0) var = 0.0;
        acc[3] = vsum;
        acc[5] = mu;
        acc[6] = 1.0 / (sqrt(var) + 1e-5);
    }
}

// ---------------------------------------------------------------------------
// P5: action loss + entropy. Fixed 4-iteration grid-stride, plain loads.
// Block partials -> pl (STORES, zero atomics).
__global__ __launch_bounds__(256) void k_loss(
    const ushort4* __restrict__ gae16,
    const float4* __restrict__ lp4,
    const float4* __restrict__ plp4,
    const float4* __restrict__ ent4,
    const double* __restrict__ acc,
    double* __restrict__ pl)           // [LOSS_BLOCKS][2]
{
    const int tid = blockIdx.x * 256 + threadIdx.x;
    const float mu   = (float)acc[5];
    const float invs = (float)acc[6];

    float a_s = 0.f, e_s = 0.f;
    #pragma unroll
    for (int k = 0; k < 4; ++k) {
        const int i = tid + k * LOSS_STRIDE;
        const ushort4 G = gae16[i];
        const float4  L = lp4[i];
        const float4  P = plp4[i];
        const float4  E = ent4[i];
        const float gs[4] = {bf2f(G.x), bf2f(G.y), bf2f(G.z), bf2f(G.w)};
        const float ls[4] = {L.x, L.y, L.z, L.w};
        const float ps[4] = {P.x, P.y, P.z, P.w};
        #pragma unroll
        for (int c = 0; c < 4; ++c) {
            const float x  = (gs[c] - mu) * invs;
            const float r  = __expf(ls[c] - ps[c]);
            const float rc = fminf(fmaxf(r, 0.8f), 1.2f);
            a_s += fminf(r * x, rc * x);
        }
        e_s += E.x + E.y + E.z + E.w;
    }

    double d0 = (double)a_s, d1 = (double)e_s;
    #pragma unroll
    for (int off = 32; off > 0; off >>= 1) {
        d0 += __shfl_down(d0, off, 64);
        d1 += __shfl_down(d1, off, 64);
    }
    __shared__ double sh[2][4];
    const int wid = threadIdx.x >> 6, lane = threadIdx.x & 63;
    if (lane == 0) { sh[0][wid] = d0; sh[1][wid] = d1; }
    __syncthreads();
    if (threadIdx.x == 0) {
        double t0s = 0, t1s = 0;
        #pragma unroll
        for (int w = 0; w < 4; ++w) { t0s += sh[0][w]; t1s += sh[1][w]; }
        pl[blockIdx.x * 2 + 0] = t0s;
        pl[blockIdx.x * 2 + 1] = t1s;
    }
}

// ---------------------------------------------------------------------------
// P6: reduce k_loss partials + combine with value sum -> final scalar.
__global__ __launch_bounds__(256) void k_final(
    const double* __restrict__ pl, const double* __restrict__ acc,
    float* __restrict__ out)
{
    double s0 = 0.0, s1 = 0.0;
    for (int i = threadIdx.x; i < LOSS_BLOCKS; i += 256) {
        s0 += pl[i * 2 + 0];
        s1 += pl[i * 2 + 1];
    }
    #pragma unroll
    for (int off = 32; off > 0; off >>= 1) {
        s0 += __shfl_down(s0, off, 64);
        s1 += __shfl_down(s1, off, 64);
    }
    __shared__ double sh[2][4];
    const int wid = threadIdx.x >> 6, lane = threadIdx.x & 63;
    if (lane == 0) { sh[0][wid] = s0; sh[1][wid] = s1; }
    __syncthreads();
    if (threadIdx.x == 0) {
        double a_sum = 0, e_sum = 0;
        #pragma unroll
        for (int w = 0; w < 4; ++w) { a_sum += sh[0][w]; e_sum += sh[1][w]; }
        const double M = (double)M_TOT;
        out[0] = (float)(0.25 * acc[3] / M - a_sum / M - 0.01 * e_sum / M);
    }
}

// ---------------------------------------------------------------------------
extern "C" void kernel_launch(void* const* d_in, const int* in_sizes, int n_in,
                              void* d_out, int out_size, void* d_ws, size_t ws_size,
                              hipStream_t stream) {
    const float* rewards     = (const float*)d_in[0];   // (T, N)
    const float* masks       = (const float*)d_in[1];   // (T+1, N)
    const float* bad_masks   = (const float*)d_in[2];   // (T+1, N)
    const float* value_preds = (const float*)d_in[3];   // (T+1, N)
    const float* last_value  = (const float*)d_in[4];   // (N,)
    const float* log_prob    = (const float*)d_in[5];   // (T, N)
    const float* prev_lp     = (const float*)d_in[6];   // (T, N)
    const float* new_value   = (const float*)d_in[7];   // (T, N)
    const float* dist_ent    = (const float*)d_in[8];   // (T, N)

    char* ws = (char*)d_ws;
    double* acc = (double*)ws;
    double* pg  = (double*)(ws + 256);
    double* pl  = (double*)(ws + 32768);
    unsigned short* b16 = (unsigned short*)(ws + 65536);
    float* A = (float*)(ws + 65536 + (size_t)M_TOT * 2);
    float* B = (float*)(ws + 65536 + (size_t)M_TOT * 2 + (size_t)C_CHUNKS * N_DIM * 4);

    k_pc<<<PC_BLOCKS, 256, 0, stream>>>((const float4*)rewards,
                                        (const float4*)masks,
                                        (const float4*)bad_masks,
                                        (const float4*)value_preds,
                                        (const float4*)last_value,
                                        (ushort4*)b16, (float4*)A, (float4*)B);
    k_ginc<<<N_DIM / 256, 256, 0, stream>>>(A, B, A /* g_in aliases A */);
    k_gae<<<PC_BLOCKS, 256, 0, stream>>>((ushort4*)b16,
                                         (const float4*)A /* g_in */,
                                         (const float4*)value_preds,
                                         (const float4*)new_value, pg);
    k_stats<<<1, 256, 0, stream>>>(pg, acc);
    k_loss<<<LOSS_BLOCKS, 256, 0, stream>>>((const ushort4*)b16 /* gae16 */,
                                            (const float4*)log_prob,
                                            (const float4*)prev_lp,
                                            (const float4*)dist_ent, acc, pl);
    k_final<<<1, 256, 0, stream>>>(pl, acc, (float*)d_out);
}